// Round 7
// baseline (218.849 us; speedup 1.0000x reference)
//
#include <hip/hip_runtime.h>
#include <hip/hip_bf16.h>

#define D_MODEL 1024
#define ADAPT   128
#define NUM_LIB 8
#define BATCH   1024
#define CH      32
#define BK      256

#define XS_STR  264   // 256+8 shorts; /8 = 33 granules (odd) -> b128 conflict-free
#define WT_STR  264
#define HS_STR  136
#define WT2_STR 136
// Phase A needs CH*XS_STR + 64*WT_STR = 8448+16896 = 25344 shorts (50688 B).
// Phase B needs CH*HS_STR + 128*WT2_STR = 4352+17408 = 21760 shorts. Overlaid.
#define POOL_SH (CH * XS_STR + 64 * WT_STR)

typedef __attribute__((ext_vector_type(8))) short bf16x8;
typedef __attribute__((ext_vector_type(4))) float f32x4;

// 2x f32 -> packed bf16 (v_cvt_pk_bf16_f32 on gfx950), RNE.
__device__ __forceinline__ unsigned pk2(float a, float b) {
  __hip_bfloat162 h = __float22bfloat162_rn(make_float2(a, b));
  return *(unsigned*)&h;
}

// ---------------------------------------------------------------------------
// Fused kernel. grid = (64 pairs, 8). Block (p,y):
//   phase A: gemm1 piece (a-half = y&1, k-quarter = y>>1) -> Hp, signal done[p]
//   phase B: stage W2 d-slice (y*128), wait done[p]==8 producers, gemm2 -> out
// done[] starts at 0xAAAAAAAA (harness ws poison) -> target = 0xAAAAAAAA + 8.
// Deadlock-free: every block signals before waiting; LDS 52.7 KB -> 3 blk/CU
// -> 768 slots >= 512 blocks, all co-resident.
// ---------------------------------------------------------------------------
__global__ __launch_bounds__(256) void fused_k(const float* __restrict__ x,
                                               const float* __restrict__ W1,
                                               const float* __restrict__ b1,
                                               const float* __restrict__ W2,
                                               const float* __restrict__ b2,
                                               const int* __restrict__ src,
                                               const int* __restrict__ tgt,
                                               float* __restrict__ Hp,
                                               unsigned* __restrict__ done,
                                               float* __restrict__ out) {
  int p = blockIdx.x, y = blockIdx.y, t = threadIdx.x;
  __shared__ int nrows;
  __shared__ unsigned short rows_l[BATCH];
  __shared__ short pool[POOL_SH];
  if (t == 0) nrows = 0;
  __syncthreads();
  {  // self-bucket: append rows with pair==p (order irrelevant: row-keyed I/O)
#pragma unroll
    for (int i = 0; i < 4; i++) {
      int s = t + 256 * i;
      if (src[s] * NUM_LIB + tgt[s] == p) rows_l[atomicAdd(&nrows, 1)] = (unsigned short)s;
    }
  }
  int lane = t & 63, wvid = t >> 6, col = lane & 15, quad = lane >> 4;

  if ((p % 9) == 0) {                  // identity pair: exact copy x -> out, d-slice y
    __syncthreads();
    int n = nrows;
    int d0 = y * 128;
    int j = t & 7;                     // 8 threads/row x 16 floats
    for (int c = t >> 3; c < n; c += 32) {
      size_t off = (size_t)rows_l[c] * D_MODEL + d0 + j * 16;
      float4 v0 = *(const float4*)(x + off);
      float4 v1 = *(const float4*)(x + off + 4);
      float4 v2 = *(const float4*)(x + off + 8);
      float4 v3 = *(const float4*)(x + off + 12);
      *(float4*)(out + off)      = v0;
      *(float4*)(out + off + 4)  = v1;
      *(float4*)(out + off + 8)  = v2;
      *(float4*)(out + off + 12) = v3;
    }
    return;
  }

  // ---------------- phase A: gemm1 piece ----------------
  short* xs = pool;                    // [CH][XS_STR]
  short* wt = pool + CH * XS_STR;      // [64][WT_STR]
  int a0 = (y & 1) * 64;
  int k0 = (y >> 1) * BK;
  {  // stage W1[k0..k0+255][a0..a0+63] -> wt[a][kl] (independent of bucketing)
    int a_st = t & 63, kg = t >> 6;    // a-lane, k-group of 64
    const float* wr = W1 + ((size_t)p * D_MODEL + k0 + kg * 64) * ADAPT + a0 + a_st;
    uint4* ww = (uint4*)(wt + a_st * WT_STR + kg * 64);
#pragma unroll
    for (int j8 = 0; j8 < 8; j8++) {
      uint4 o;
      o.x = pk2(wr[(j8 * 8 + 0) * ADAPT], wr[(j8 * 8 + 1) * ADAPT]);
      o.y = pk2(wr[(j8 * 8 + 2) * ADAPT], wr[(j8 * 8 + 3) * ADAPT]);
      o.z = pk2(wr[(j8 * 8 + 4) * ADAPT], wr[(j8 * 8 + 5) * ADAPT]);
      o.w = pk2(wr[(j8 * 8 + 6) * ADAPT], wr[(j8 * 8 + 7) * ADAPT]);
      ww[j8] = o;
    }
  }
  __syncthreads();                     // bucketing + wt staging complete
  int n = nrows;
  float* Hb = Hp + (size_t)(y >> 1) * BATCH * ADAPT;
  if (n > 0) {
    for (int c0 = 0; c0 < n; c0 += CH) {
      int m = min(CH, n - c0);
      {  // stage X chunk: thread (s=t&31, jg=t>>5) covers k's jg*32..+31
        int s = t & 31, jg = t >> 5;
        int row = rows_l[c0 + min(s, m - 1)];
        const float* xr = x + (size_t)row * D_MODEL + k0 + jg * 32;
        uint4* xw = (uint4*)(xs + s * XS_STR + jg * 32);
#pragma unroll
        for (int i = 0; i < 4; i++) {
          float4 v0 = *(const float4*)(xr + i * 8);
          float4 v1 = *(const float4*)(xr + i * 8 + 4);
          uint4 o;
          o.x = pk2(v0.x, v0.y); o.y = pk2(v0.z, v0.w);
          o.z = pk2(v1.x, v1.y); o.w = pk2(v1.z, v1.w);
          xw[i] = o;
        }
      }
      __syncthreads();
      f32x4 acc0 = {0.f, 0.f, 0.f, 0.f};   // rows 0-15
      f32x4 acc1 = {0.f, 0.f, 0.f, 0.f};   // rows 16-31
#pragma unroll
      for (int kk = 0; kk < 8; kk++) {
        bf16x8 af0 = *(const bf16x8*)(xs + col * XS_STR + kk * 32 + quad * 8);
        bf16x8 af1 = *(const bf16x8*)(xs + (16 + col) * XS_STR + kk * 32 + quad * 8);
        bf16x8 bv  = *(const bf16x8*)(wt + (wvid * 16 + col) * WT_STR + kk * 32 + quad * 8);
        acc0 = __builtin_amdgcn_mfma_f32_16x16x32_bf16(af0, bv, acc0, 0, 0, 0);
        acc1 = __builtin_amdgcn_mfma_f32_16x16x32_bf16(af1, bv, acc1, 0, 0, 0);
      }
      int a = a0 + wvid * 16 + col;
#pragma unroll
      for (int r = 0; r < 4; r++) {
        int s2 = quad * 4 + r;
        if (s2 < m)      Hb[(size_t)rows_l[c0 + s2] * ADAPT + a]      = acc0[r];
        if (s2 + 16 < m) Hb[(size_t)rows_l[c0 + s2 + 16] * ADAPT + a] = acc1[r];
      }
      __syncthreads();                 // protect xs/wt (pool reuse + next chunk)
    }
  }
  // Release: make Hp writes device-visible, then signal.
  __threadfence();
  __syncthreads();
  if (t == 0)
    __hip_atomic_fetch_add(done + p, 1u, __ATOMIC_RELEASE, __HIP_MEMORY_SCOPE_AGENT);
  if (n == 0) return;                  // no consumers wait in this case

  // ---------------- phase B: gemm2 d-slice ----------------
  short* hs  = pool;                   // [CH][HS_STR]
  short* wt2 = pool + CH * HS_STR;     // [128][WT2_STR]
  int d0 = y * 128;
  {  // stage W2[0..127][d0..d0+127] -> wt2[d][k] (overlaps other producers)
    int dl = t & 127, half = t >> 7;
#pragma unroll
    for (int kgi = 0; kgi < 8; kgi++) {
      int kb = kgi * 16 + half * 8;
      const float* wr = W2 + ((size_t)p * ADAPT + kb) * D_MODEL + d0 + dl;
      uint4 o;
      o.x = pk2(wr[0 * D_MODEL], wr[1 * D_MODEL]);
      o.y = pk2(wr[2 * D_MODEL], wr[3 * D_MODEL]);
      o.z = pk2(wr[4 * D_MODEL], wr[5 * D_MODEL]);
      o.w = pk2(wr[6 * D_MODEL], wr[7 * D_MODEL]);
      *(uint4*)(wt2 + dl * WT2_STR + kb) = o;
    }
  }
  // Wait for all 8 producers of this pair (incl. self).
  if (t == 0) {
    const unsigned target = 0xAAAAAAAAu + 8u;  // ws poison + 8 signals
    while (__hip_atomic_load(done + p, __ATOMIC_ACQUIRE, __HIP_MEMORY_SCOPE_AGENT) != target)
      __builtin_amdgcn_s_sleep(2);
  }
  __syncthreads();
  __threadfence();                     // acquire: invalidate stale cached Hp
  for (int c0 = 0; c0 < n; c0 += CH) {
    int m = min(CH, n - c0);
    {  // stage H chunk: sum 4 split-K partials + bias + relu, fp32 -> bf16
      int s = t & 31, j = t >> 5;      // k-range j*16..+15
      int row = rows_l[c0 + min(s, m - 1)];
      size_t ho = (size_t)row * ADAPT + j * 16;
      const float* bb = b1 + (size_t)p * ADAPT + j * 16;
      uint4* hw = (uint4*)(hs + s * HS_STR + j * 16);
#pragma unroll
      for (int g = 0; g < 2; g++) {
        float v[8];
#pragma unroll
        for (int i = 0; i < 8; i++) {
          float acc = bb[g * 8 + i];
#pragma unroll
          for (int q = 0; q < 4; q++) acc += Hp[(size_t)q * BATCH * ADAPT + ho + g * 8 + i];
          v[i] = fmaxf(acc, 0.f);
        }
        uint4 o;
        o.x = pk2(v[0], v[1]); o.y = pk2(v[2], v[3]);
        o.z = pk2(v[4], v[5]); o.w = pk2(v[6], v[7]);
        hw[g] = o;
      }
    }
    __syncthreads();
    f32x4 acc00 = {0.f, 0.f, 0.f, 0.f};  // rows 0-15,  d_a
    f32x4 acc01 = {0.f, 0.f, 0.f, 0.f};  // rows 0-15,  d_b
    f32x4 acc10 = {0.f, 0.f, 0.f, 0.f};  // rows 16-31, d_a
    f32x4 acc11 = {0.f, 0.f, 0.f, 0.f};  // rows 16-31, d_b
#pragma unroll
    for (int kk = 0; kk < 4; kk++) {
      bf16x8 af0 = *(const bf16x8*)(hs + col * HS_STR + kk * 32 + quad * 8);
      bf16x8 af1 = *(const bf16x8*)(hs + (16 + col) * HS_STR + kk * 32 + quad * 8);
      bf16x8 b0  = *(const bf16x8*)(wt2 + (wvid * 32 + col) * WT2_STR + kk * 32 + quad * 8);
      bf16x8 b1v = *(const bf16x8*)(wt2 + (wvid * 32 + 16 + col) * WT2_STR + kk * 32 + quad * 8);
      acc00 = __builtin_amdgcn_mfma_f32_16x16x32_bf16(af0, b0,  acc00, 0, 0, 0);
      acc01 = __builtin_amdgcn_mfma_f32_16x16x32_bf16(af0, b1v, acc01, 0, 0, 0);
      acc10 = __builtin_amdgcn_mfma_f32_16x16x32_bf16(af1, b0,  acc10, 0, 0, 0);
      acc11 = __builtin_amdgcn_mfma_f32_16x16x32_bf16(af1, b1v, acc11, 0, 0, 0);
    }
    int d_a = d0 + wvid * 32 + col;
    int d_b = d_a + 16;
    float bba = b2[(size_t)p * D_MODEL + d_a];
    float bbb = b2[(size_t)p * D_MODEL + d_b];
#pragma unroll
    for (int r = 0; r < 4; r++) {
      int s2 = quad * 4 + r;
      if (s2 < m) {
        size_t ro = (size_t)rows_l[c0 + s2] * D_MODEL;
        out[ro + d_a] = acc00[r] + bba;
        out[ro + d_b] = acc01[r] + bbb;
      }
      if (s2 + 16 < m) {
        size_t ro = (size_t)rows_l[c0 + s2 + 16] * D_MODEL;
        out[ro + d_a] = acc10[r] + bba;
        out[ro + d_b] = acc11[r] + bbb;
      }
    }
    if (c0 + CH < n) __syncthreads();  // protect hs before next chunk's staging
  }
}

// ---------------------------------------------------------------------------
extern "C" void kernel_launch(void* const* d_in, const int* in_sizes, int n_in,
                              void* d_out, int out_size, void* d_ws, size_t ws_size,
                              hipStream_t stream) {
  const float* x   = (const float*)d_in[0];
  const int*   src = (const int*)d_in[1];
  const int*   tgt = (const int*)d_in[2];
  const float* W1  = (const float*)d_in[3];
  const float* b1  = (const float*)d_in[4];
  const float* W2  = (const float*)d_in[5];
  const float* b2  = (const float*)d_in[6];
  float* out = (float*)d_out;

  // ws layout: Hp [4][1024*128] floats (split-K partials), then done[64]
  // (starts at 0xAAAAAAAA from harness poison -> target = 0xAAAAAAAA+8).
  float* Hp       = (float*)d_ws;
  unsigned* done  = (unsigned*)(Hp + 4 * (size_t)BATCH * ADAPT);

  fused_k<<<dim3(64, 8), 256, 0, stream>>>(x, W1, b1, W2, b2, src, tgt, Hp, done, out);
  (void)in_sizes; (void)n_in; (void)out_size; (void)ws_size;
}

// Round 8
// 116.053 us; speedup vs baseline: 1.8858x; 1.8858x over previous
//
#include <hip/hip_runtime.h>
#include <hip/hip_bf16.h>

#define D_MODEL 1024
#define ADAPT   128
#define NUM_LIB 8
#define BATCH   1024
#define CH      32

typedef __attribute__((ext_vector_type(8))) short bf16x8;
typedef __attribute__((ext_vector_type(4))) float f32x4;

// 2x f32 -> packed bf16 (v_cvt_pk_bf16_f32 on gfx950), RNE.
__device__ __forceinline__ unsigned pk2(float a, float b) {
  __hip_bfloat162 h = __float22bfloat162_rn(make_float2(a, b));
  return *(unsigned*)&h;
}

// ---------------------------------------------------------------------------
// Kernel 1: partial H = X @ W1[p], bf16 MFMA, M=32, split-K x4.
// grid = (64 pairs, 2 a-halves, 4 k-quarters). Self-bucketing: each block
// scans src/tgt and builds its own row list (order irrelevant: row-keyed I/O).
// NOTE (R7 post-mortem): do NOT fuse gemm1/gemm2 with a cross-block spin
// barrier — agent-scope ACQUIRE spin + threadfence cost ~125us of idle waves
// on MI355X. The kernel boundary (~2us) is the cheap way to express the
// producer->consumer dependency.
// ---------------------------------------------------------------------------
#define BK     256
#define XS_STR 264   // 256+8 shorts; /8 = 33 granules (odd) -> b128 conflict-free
#define WT_STR 264

__global__ __launch_bounds__(256) void gemm1_k(const float* __restrict__ x,
                                               const float* __restrict__ W1,
                                               const int* __restrict__ src,
                                               const int* __restrict__ tgt,
                                               float* __restrict__ Hp) {
  int p = blockIdx.x;
  if ((p % 9) == 0) return;            // diagonal pair: identity path
  int a0 = blockIdx.y * 64;
  int k0 = blockIdx.z * BK;            // k-quarter
  __shared__ int   nrows;
  __shared__ int   rows_l[BATCH];
  __shared__ short xs[CH * XS_STR];    // X chunk bf16 [s][kl], kl in [0,256)
  __shared__ short wt[64 * WT_STR];    // W1 tile bf16 [a][kl]
  int t = threadIdx.x;
  if (t == 0) nrows = 0;
  __syncthreads();
  {  // self-bucket: append rows with pair==p (order irrelevant)
#pragma unroll
    for (int i = 0; i < 4; i++) {
      int s = t + 256 * i;
      int pr = src[s] * NUM_LIB + tgt[s];
      if (pr == p) rows_l[atomicAdd(&nrows, 1)] = s;
    }
  }
  {  // stage W1[k0..k0+255][a0..a0+63] -> wt[a][kl] (independent of bucketing)
    int a_st = t & 63, kg = t >> 6;    // a-lane, k-group of 64
    const float* wr = W1 + ((size_t)p * D_MODEL + k0 + kg * 64) * ADAPT + a0 + a_st;
    uint4* ww = (uint4*)(wt + a_st * WT_STR + kg * 64);
#pragma unroll
    for (int j8 = 0; j8 < 8; j8++) {
      uint4 o;
      o.x = pk2(wr[(j8 * 8 + 0) * ADAPT], wr[(j8 * 8 + 1) * ADAPT]);
      o.y = pk2(wr[(j8 * 8 + 2) * ADAPT], wr[(j8 * 8 + 3) * ADAPT]);
      o.z = pk2(wr[(j8 * 8 + 4) * ADAPT], wr[(j8 * 8 + 5) * ADAPT]);
      o.w = pk2(wr[(j8 * 8 + 6) * ADAPT], wr[(j8 * 8 + 7) * ADAPT]);
      ww[j8] = o;
    }
  }
  __syncthreads();                     // covers bucketing + wt staging
  int n = nrows;
  if (n == 0) return;
  int lane = t & 63, wvid = t >> 6, col = lane & 15, quad = lane >> 4;
  float* Hb = Hp + (size_t)blockIdx.z * BATCH * ADAPT;
  for (int c0 = 0; c0 < n; c0 += CH) {
    int m = min(CH, n - c0);
    {  // stage X chunk: thread (s=t&31, jg=t>>5) covers k's jg*32..+31
      int s = t & 31, jg = t >> 5;
      int row = rows_l[c0 + min(s, m - 1)];
      const float* xr = x + (size_t)row * D_MODEL + k0 + jg * 32;
      uint4* xw = (uint4*)(xs + s * XS_STR + jg * 32);
#pragma unroll
      for (int i = 0; i < 4; i++) {
        float4 v0 = *(const float4*)(xr + i * 8);
        float4 v1 = *(const float4*)(xr + i * 8 + 4);
        uint4 o;
        o.x = pk2(v0.x, v0.y); o.y = pk2(v0.z, v0.w);
        o.z = pk2(v1.x, v1.y); o.w = pk2(v1.z, v1.w);
        xw[i] = o;
      }
    }
    __syncthreads();
    f32x4 acc0 = {0.f, 0.f, 0.f, 0.f};   // rows 0-15
    f32x4 acc1 = {0.f, 0.f, 0.f, 0.f};   // rows 16-31
#pragma unroll
    for (int kk = 0; kk < 8; kk++) {
      bf16x8 af0 = *(const bf16x8*)(xs + col * XS_STR + kk * 32 + quad * 8);
      bf16x8 af1 = *(const bf16x8*)(xs + (16 + col) * XS_STR + kk * 32 + quad * 8);
      bf16x8 bv  = *(const bf16x8*)(wt + (wvid * 16 + col) * WT_STR + kk * 32 + quad * 8);
      acc0 = __builtin_amdgcn_mfma_f32_16x16x32_bf16(af0, bv, acc0, 0, 0, 0);
      acc1 = __builtin_amdgcn_mfma_f32_16x16x32_bf16(af1, bv, acc1, 0, 0, 0);
    }
    int a = a0 + wvid * 16 + col;
#pragma unroll
    for (int r = 0; r < 4; r++) {
      int s2 = quad * 4 + r;
      if (s2 < m)      Hb[(size_t)rows_l[c0 + s2] * ADAPT + a]      = acc0[r];
      if (s2 + 16 < m) Hb[(size_t)rows_l[c0 + s2 + 16] * ADAPT + a] = acc1[r];
    }
    if (c0 + CH < n) __syncthreads();  // protect xs before next chunk's staging
  }
}

// ---------------------------------------------------------------------------
// Kernel 2: out[rows, d0..d0+127] = relu(sum Hp + b1) @ W2[p][:, d0..] + b2
// (or copy x for diagonal pairs). grid = (64 pairs, 8 d-slices). M=32.
// ---------------------------------------------------------------------------
#define HS_STR  136
#define WT2_STR 136

__global__ __launch_bounds__(256) void gemm2_k(const float* __restrict__ x,
                                               const float* __restrict__ W2,
                                               const float* __restrict__ b1,
                                               const float* __restrict__ b2,
                                               const int* __restrict__ src,
                                               const int* __restrict__ tgt,
                                               const float* __restrict__ Hp,
                                               float* __restrict__ out) {
  int p = blockIdx.x;
  int d0 = blockIdx.y * 128;
  __shared__ int nrows;
  __shared__ int rows_l[BATCH];
  int t = threadIdx.x;
  if (t == 0) nrows = 0;
  __syncthreads();
  {  // self-bucket
#pragma unroll
    for (int i = 0; i < 4; i++) {
      int s = t + 256 * i;
      int pr = src[s] * NUM_LIB + tgt[s];
      if (pr == p) rows_l[atomicAdd(&nrows, 1)] = s;
    }
  }
  if ((p % 9) == 0) {                  // identity: exact copy x -> out
    __syncthreads();
    int n = nrows;
    int j = t & 7;                     // 8 threads/row x 16 floats
    for (int c = t >> 3; c < n; c += 32) {
      size_t off = (size_t)rows_l[c] * D_MODEL + d0 + j * 16;
      float4 v0 = *(const float4*)(x + off);
      float4 v1 = *(const float4*)(x + off + 4);
      float4 v2 = *(const float4*)(x + off + 8);
      float4 v3 = *(const float4*)(x + off + 12);
      *(float4*)(out + off)      = v0;
      *(float4*)(out + off + 4)  = v1;
      *(float4*)(out + off + 8)  = v2;
      *(float4*)(out + off + 12) = v3;
    }
    return;
  }
  __shared__ short hs[CH * HS_STR];     // relu(sum Hp + b1) bf16 [s][k]
  __shared__ short wt[128 * WT2_STR];   // W2 slice bf16 [d][k] (transposed)
  {  // stage W2[0..127][d0..d0+127] -> wt[d][k] (independent of bucketing)
    int dl = t & 127, half = t >> 7;
#pragma unroll
    for (int kgi = 0; kgi < 8; kgi++) {
      int kb = kgi * 16 + half * 8;
      const float* wr = W2 + ((size_t)p * ADAPT + kb) * D_MODEL + d0 + dl;
      uint4 o;
      o.x = pk2(wr[0 * D_MODEL], wr[1 * D_MODEL]);
      o.y = pk2(wr[2 * D_MODEL], wr[3 * D_MODEL]);
      o.z = pk2(wr[4 * D_MODEL], wr[5 * D_MODEL]);
      o.w = pk2(wr[6 * D_MODEL], wr[7 * D_MODEL]);
      *(uint4*)(wt + dl * WT2_STR + kb) = o;
    }
  }
  __syncthreads();                     // covers bucketing + wt staging
  int n = nrows;
  if (n == 0) return;
  int lane = t & 63, wvid = t >> 6, col = lane & 15, quad = lane >> 4;
  for (int c0 = 0; c0 < n; c0 += CH) {
    int m = min(CH, n - c0);
    {  // stage H chunk: sum 4 split-K partials + bias + relu, fp32 -> bf16
      int s = t & 31, j = t >> 5;      // k-range j*16..+15
      int row = rows_l[c0 + min(s, m - 1)];
      size_t ho = (size_t)row * ADAPT + j * 16;
      const float* bb = b1 + (size_t)p * ADAPT + j * 16;
      uint4* hw = (uint4*)(hs + s * HS_STR + j * 16);
#pragma unroll
      for (int g = 0; g < 2; g++) {
        float v[8];
#pragma unroll
        for (int i = 0; i < 8; i++) {
          float acc = bb[g * 8 + i];
#pragma unroll
          for (int q = 0; q < 4; q++) acc += Hp[(size_t)q * BATCH * ADAPT + ho + g * 8 + i];
          v[i] = fmaxf(acc, 0.f);
        }
        uint4 o;
        o.x = pk2(v[0], v[1]); o.y = pk2(v[2], v[3]);
        o.z = pk2(v[4], v[5]); o.w = pk2(v[6], v[7]);
        hw[g] = o;
      }
    }
    __syncthreads();
    f32x4 acc00 = {0.f, 0.f, 0.f, 0.f};  // rows 0-15,  d_a
    f32x4 acc01 = {0.f, 0.f, 0.f, 0.f};  // rows 0-15,  d_b
    f32x4 acc10 = {0.f, 0.f, 0.f, 0.f};  // rows 16-31, d_a
    f32x4 acc11 = {0.f, 0.f, 0.f, 0.f};  // rows 16-31, d_b
#pragma unroll
    for (int kk = 0; kk < 4; kk++) {
      bf16x8 af0 = *(const bf16x8*)(hs + col * HS_STR + kk * 32 + quad * 8);
      bf16x8 af1 = *(const bf16x8*)(hs + (16 + col) * HS_STR + kk * 32 + quad * 8);
      bf16x8 b0  = *(const bf16x8*)(wt + (wvid * 32 + col) * WT2_STR + kk * 32 + quad * 8);
      bf16x8 b1v = *(const bf16x8*)(wt + (wvid * 32 + 16 + col) * WT2_STR + kk * 32 + quad * 8);
      acc00 = __builtin_amdgcn_mfma_f32_16x16x32_bf16(af0, b0,  acc00, 0, 0, 0);
      acc01 = __builtin_amdgcn_mfma_f32_16x16x32_bf16(af0, b1v, acc01, 0, 0, 0);
      acc10 = __builtin_amdgcn_mfma_f32_16x16x32_bf16(af1, b0,  acc10, 0, 0, 0);
      acc11 = __builtin_amdgcn_mfma_f32_16x16x32_bf16(af1, b1v, acc11, 0, 0, 0);
    }
    int d_a = d0 + wvid * 32 + col;
    int d_b = d_a + 16;
    float bba = b2[(size_t)p * D_MODEL + d_a];
    float bbb = b2[(size_t)p * D_MODEL + d_b];
#pragma unroll
    for (int r = 0; r < 4; r++) {
      int s2 = quad * 4 + r;
      if (s2 < m) {
        size_t ro = (size_t)rows_l[c0 + s2] * D_MODEL;
        out[ro + d_a] = acc00[r] + bba;
        out[ro + d_b] = acc01[r] + bbb;
      }
      if (s2 + 16 < m) {
        size_t ro = (size_t)rows_l[c0 + s2 + 16] * D_MODEL;
        out[ro + d_a] = acc10[r] + bba;
        out[ro + d_b] = acc11[r] + bbb;
      }
    }
    if (c0 + CH < n) __syncthreads();  // protect hs before next chunk's staging
  }
}

// ---------------------------------------------------------------------------
extern "C" void kernel_launch(void* const* d_in, const int* in_sizes, int n_in,
                              void* d_out, int out_size, void* d_ws, size_t ws_size,
                              hipStream_t stream) {
  const float* x   = (const float*)d_in[0];
  const int*   src = (const int*)d_in[1];
  const int*   tgt = (const int*)d_in[2];
  const float* W1  = (const float*)d_in[3];
  const float* b1  = (const float*)d_in[4];
  const float* W2  = (const float*)d_in[5];
  const float* b2  = (const float*)d_in[6];
  float* out = (float*)d_out;

  // ws layout: Hp [4][1024*128] floats (split-K partials).
  float* Hp = (float*)d_ws;

  gemm1_k<<<dim3(64, 2, 4), 256, 0, stream>>>(x, W1, src, tgt, Hp);
  gemm2_k<<<dim3(64, 8), 256, 0, stream>>>(x, W2, b1, b2, src, tgt, Hp, out);
  (void)in_sizes; (void)n_in; (void)out_size; (void)ws_size;
}